// Round 8
// baseline (307.336 us; speedup 1.0000x reference)
//
#include <hip/hip_runtime.h>
#include <hip/hip_bf16.h>
#include <math.h>

#define B_   2
#define S_   2048
#define HID_ 1024
#define D_   64
#define H_   16
#define ROT_ 32
#define M_   (B_*S_)
#define NSPLIT 2
#define KSPAN (S_ / NSPLIT)      // 1024 k per split
#define NT    (KSPAN / 64)       // 16 tiles per split

typedef __attribute__((ext_vector_type(4))) short  short4v;
typedef __attribute__((ext_vector_type(8))) short  short8;
typedef __attribute__((ext_vector_type(4))) float  floatx4;
typedef __attribute__((ext_vector_type(16))) float floatx16;

__device__ __forceinline__ float bf2f(unsigned short u) {
  unsigned int x = ((unsigned int)u) << 16;
  return __builtin_bit_cast(float, x);
}
__device__ __forceinline__ unsigned short f2bf(float f) {
  unsigned int x = __builtin_bit_cast(unsigned int, f);
  x += 0x7fffu + ((x >> 16) & 1u);   // RNE; inputs finite
  return (unsigned short)(x >> 16);
}
// HW packed f32x2 -> bf16x2 (v_cvt_pk_bf16_f32 on gfx950)
__device__ __forceinline__ unsigned int pkbf(float a, float b) {
  __hip_bfloat162 h = __float22bfloat162_rn(float2{a, b});
  unsigned int u; __builtin_memcpy(&u, &h, 4); return u;
}
// async global->LDS, 16B per lane; lds dest = wave-uniform base + lane*16
__device__ __forceinline__ void gload_lds16(const unsigned short* g, unsigned short* l) {
  __builtin_amdgcn_global_load_lds(
      (const __attribute__((address_space(1))) unsigned int*)g,
      (__attribute__((address_space(3))) unsigned int*)l, 16, 0, 0);
}

// ---------------- cast x (fp32 -> bf16) ----------------
__global__ void cast_bf16(const float* __restrict__ in, unsigned short* __restrict__ out) {
  int i = (blockIdx.x * 256 + threadIdx.x) * 4;
  floatx4 v = *(const floatx4*)(in + i);
  unsigned short o[4];
  o[0] = f2bf(v[0]); o[1] = f2bf(v[1]); o[2] = f2bf(v[2]); o[3] = f2bf(v[3]);
  *(unsigned long long*)(out + i) = *(unsigned long long*)o;
}

// ------------- transpose + cast weights: T[n][k] = bf16(W[k][n]) -------------
__global__ void transW(const float* __restrict__ W0, const float* __restrict__ W1,
                       const float* __restrict__ W2, const float* __restrict__ W3,
                       unsigned short* __restrict__ T0, unsigned short* __restrict__ T1,
                       unsigned short* __restrict__ T2, unsigned short* __restrict__ T3) {
  const float* W; unsigned short* T;
  int z = blockIdx.z;
  if (z == 0)      { W = W0; T = T0; }
  else if (z == 1) { W = W1; T = T1; }
  else if (z == 2) { W = W2; T = T2; }
  else             { W = W3; T = T3; }
  __shared__ float tile[32][33];
  int bx = blockIdx.x * 32, by = blockIdx.y * 32;
  int tx = threadIdx.x, ty = threadIdx.y;
  #pragma unroll
  for (int j = 0; j < 4; j++)
    tile[ty + j*8][tx] = W[(size_t)(by + ty + j*8) * HID_ + bx + tx];
  __syncthreads();
  #pragma unroll
  for (int j = 0; j < 4; j++)
    T[(size_t)(bx + ty + j*8) * HID_ + by + tx] = f2bf(tile[tx][ty + j*8]);
}

// ---------------- GEMM: C[M,N] = A[M,K] @ Bt[N,K]^T (+bias) ----------------
// MODE 0: QKV producer. z=0: Q bf16, rope + scale c1. z=1: K bf16, rope.
//         z=2: V bf16 written TRANSPOSED into Vt[b][h][d][s].
// MODE 1: fp32 row-major out (final projection).
template <int MODE>
__global__ __launch_bounds__(256) void gemm_bt(
    const unsigned short* __restrict__ A,
    const unsigned short* __restrict__ Bt0, const unsigned short* __restrict__ Bt1,
    const unsigned short* __restrict__ Bt2,
    const float* __restrict__ bias0, const float* __restrict__ bias1,
    const float* __restrict__ bias2,
    void* __restrict__ out0, void* __restrict__ out1, void* __restrict__ out2,
    const float* __restrict__ sins, float sc0)
{
  const unsigned short* Bt; const float* bias; void* Out; float sc;
  if (blockIdx.z == 0)      { Bt = Bt0; bias = bias0; Out = out0; sc = sc0; }
  else if (blockIdx.z == 1) { Bt = Bt1; bias = bias1; Out = out1; sc = 1.f; }
  else                      { Bt = Bt2; bias = bias2; Out = out2; sc = 1.f; }
  const int K = HID_, N = HID_;
  int m0 = blockIdx.y * 128, n0 = blockIdx.x * 128;
  __shared__ alignas(16) unsigned short sA[128 * 32];
  __shared__ alignas(16) unsigned short sB[128 * 32];
  int t = threadIdx.x;
  int lane = t & 63, wave = t >> 6;
  int quad = lane >> 4, l16 = lane & 15;
  int wr = wave >> 1, wc = wave & 1;

  int srow = (lane >> 2), scol = (lane & 3) * 8;
  const unsigned short* gA0 = A  + (size_t)(m0 + wave*32 +  0 + srow) * K + scol;
  const unsigned short* gA1 = A  + (size_t)(m0 + wave*32 + 16 + srow) * K + scol;
  const unsigned short* gB0 = Bt + (size_t)(n0 + wave*32 +  0 + srow) * K + scol;
  const unsigned short* gB1 = Bt + (size_t)(n0 + wave*32 + 16 + srow) * K + scol;
  unsigned short* lA0 = sA + (wave*32 +  0) * 32;
  unsigned short* lA1 = sA + (wave*32 + 16) * 32;
  unsigned short* lB0 = sB + (wave*32 +  0) * 32;
  unsigned short* lB1 = sB + (wave*32 + 16) * 32;

  floatx4 acc[4][4];
  #pragma unroll
  for (int i = 0; i < 4; i++)
    #pragma unroll
    for (int j = 0; j < 4; j++)
      acc[i][j] = (floatx4){0.f, 0.f, 0.f, 0.f};

  for (int k0 = 0; k0 < K; k0 += 32) {
    gload_lds16(gA0 + k0, lA0);
    gload_lds16(gA1 + k0, lA1);
    gload_lds16(gB0 + k0, lB0);
    gload_lds16(gB1 + k0, lB1);
    __syncthreads();
    short8 af[4], bf[4];
    #pragma unroll
    for (int i = 0; i < 4; i++) {
      af[i] = *(const short8*)(sA + (wr * 64 + i * 16 + l16) * 32 + quad * 8);
      bf[i] = *(const short8*)(sB + (wc * 64 + i * 16 + l16) * 32 + quad * 8);
    }
    #pragma unroll
    for (int i = 0; i < 4; i++)
      #pragma unroll
      for (int j = 0; j < 4; j++)
        acc[i][j] = __builtin_amdgcn_mfma_f32_16x16x32_bf16(af[i], bf[j], acc[i][j], 0, 0, 0);
    __syncthreads();
  }

  // Epilogue. C/D layout: col = lane&15, row = quad*4 + reg.
  #pragma unroll
  for (int i = 0; i < 4; i++) {
    int mbase = m0 + wr * 64 + i * 16 + quad * 4;
    #pragma unroll
    for (int j = 0; j < 4; j++) {
      int n = n0 + wc * 64 + j * 16 + l16;
      float bv = bias ? bias[n] : 0.f;
      if (MODE == 1) {
        #pragma unroll
        for (int r = 0; r < 4; r++)
          ((float*)Out)[(size_t)(mbase + r) * N + n] = acc[i][j][r] + bv;
      } else if (blockIdx.z == 2) {
        // V: write transposed Vt[((b*16+h)*64+dd)*2048 + s], 4 consecutive s packed
        int bb = mbase >> 11, ss = mbase & 2047;
        int hh = n >> 6, dd = n & 63;
        unsigned short pk[4];
        #pragma unroll
        for (int r = 0; r < 4; r++) pk[r] = f2bf(acc[i][j][r] + bv);
        *(unsigned long long*)((unsigned short*)Out +
            (((size_t)(bb * H_ + hh) * D_ + dd) * S_ + ss)) = *(unsigned long long*)pk;
      } else if (j < 2) {
        // rope columns: head-dim index jh = j*16 + l16 < 32 (wave-uniform branch)
        int jh = j * 16 + l16;
        #pragma unroll
        for (int r = 0; r < 4; r++) {
          int row = mbase + r, bb = row >> 11, ss = row & 2047;
          float sn = sins[((size_t)(bb * 2 + 0) * S_ + ss) * ROT_ + jh];
          float cs = sins[((size_t)(bb * 2 + 1) * S_ + ss) * ROT_ + jh];
          float f = (jh & 1) ? (cs + sn) : (cs - sn);
          ((unsigned short*)Out)[(size_t)row * N + n] = f2bf((acc[i][j][r] + bv) * f * sc);
        }
      } else {
        #pragma unroll
        for (int r = 0; r < 4; r++)
          ((unsigned short*)Out)[(size_t)(mbase + r) * N + n] = f2bf((acc[i][j][r] + bv) * sc);
      }
    }
  }
}

// ------ flash attention v5: S^T trick + split-K + 2 HEADS PER BLOCK (shared bias) ------
// bias is head-independent (B,1,S,S): one block computes heads {2hp, 2hp+1} for a
// (qtile,b,split), loading each bias tile ONCE into regs and using it for both heads.
// Bias traffic halves (512->256 MB/call). K/V double-buffered per head (73.7 KB LDS,
// 2 blocks/CU). Grid 512, gid = hp*64 + combo so same-combo blocks share an XCD L2.
__global__ __launch_bounds__(256) void attn(
    const unsigned short* __restrict__ Q, const unsigned short* __restrict__ Kb,
    const unsigned short* __restrict__ Vt, const float* __restrict__ bias,
    float* __restrict__ Opart, float* __restrict__ Lpart)
{
  int gid = blockIdx.x;
  int hp = gid >> 6;                 // head pair [0,8)
  int combo = gid & 63;
  int qtile = combo & 15;
  int b = (combo >> 4) & 1, split = combo >> 5;

  int t = threadIdx.x;
  int lane = t & 63, wave = t >> 6;
  int l32 = lane & 31, hl = lane >> 5;
  int q0 = qtile * 128 + wave * 32;
  int kbase = split * KSPAN;
  const int RS = H_ * D_;

  __shared__ alignas(16) unsigned short sK[2][2][64 * 72];  // [buf][head][k][d] pad 72
  __shared__ alignas(16) unsigned short sV[2][2][64 * 72];  // [buf][head][d][k] pad 72

  // per-head bases
  const unsigned short* Qb0 = Q + ((size_t)(b * S_) * H_ + hp * 2) * D_;
  const unsigned short* Kb0 = Kb + ((size_t)(b * S_ + kbase) * H_ + hp * 2) * D_;
  const unsigned short* Vb0 = Vt + (((size_t)(b * H_) + hp * 2) * D_) * S_ + kbase;

  // Q B-frags (n=q=lane&31, k=d=16s+8hl+j) for both heads
  short8 qf[2][4];
  #pragma unroll
  for (int hh = 0; hh < 2; hh++) {
    const unsigned short* qp = Qb0 + (size_t)hh * D_ + (size_t)(q0 + l32) * RS + 8 * hl;
    qf[hh][0] = *(const short8*)(qp);
    qf[hh][1] = *(const short8*)(qp + 16);
    qf[hh][2] = *(const short8*)(qp + 32);
    qf[hh][3] = *(const short8*)(qp + 48);
  }

  // staging: thread t -> row t>>2, quarter t&3, 2x16B chunks, per head
  int srow = t >> 2, sq = t & 3;
  const unsigned short* gK[2]; const unsigned short* gV[2];
  #pragma unroll
  for (int hh = 0; hh < 2; hh++) {
    gK[hh] = Kb0 + (size_t)srow * RS + (size_t)hh * D_ + sq * 16;
    gV[hh] = Vb0 + ((size_t)hh * D_ + srow) * S_ + sq * 16;
  }
  const int wOff = srow * 72 + sq * 16;

  // bias row for this lane's q (shared by both heads)
  const float* bp = bias + (size_t)b * S_ * S_ + (size_t)(q0 + l32) * S_ + kbase + 4 * hl;

  float l_run[2] = {0.f, 0.f};
  floatx16 oacc[2][2];
  #pragma unroll
  for (int hh = 0; hh < 2; hh++)
    #pragma unroll
    for (int r = 0; r < 16; r++) { oacc[hh][0][r] = 0.f; oacc[hh][1][r] = 0.f; }

  // tile 0 -> LDS buf 0 (both heads)
  floatx4 kp[2][2], vp[2][2];
  #pragma unroll
  for (int hh = 0; hh < 2; hh++) {
    kp[hh][0] = *(const floatx4*)(gK[hh]);  kp[hh][1] = *(const floatx4*)(gK[hh] + 8);
    vp[hh][0] = *(const floatx4*)(gV[hh]);  vp[hh][1] = *(const floatx4*)(gV[hh] + 8);
    *(floatx4*)(&sK[0][hh][wOff])     = kp[hh][0];
    *(floatx4*)(&sK[0][hh][wOff + 8]) = kp[hh][1];
    *(floatx4*)(&sV[0][hh][wOff])     = vp[hh][0];
    *(floatx4*)(&sV[0][hh][wOff + 8]) = vp[hh][1];
  }
  // prefetch tile 1
  #pragma unroll
  for (int hh = 0; hh < 2; hh++) {
    kp[hh][0] = *(const floatx4*)(gK[hh] + (size_t)64 * RS);
    kp[hh][1] = *(const floatx4*)(gK[hh] + (size_t)64 * RS + 8);
    vp[hh][0] = *(const floatx4*)(gV[hh] + 64);
    vp[hh][1] = *(const floatx4*)(gV[hh] + 64 + 8);
  }

  for (int it = 0; it < NT; ++it) {
    int cur = it & 1, nxt = cur ^ 1;
    int kt = it * 64;   // k offset within split
    __syncthreads();

    if (it < NT - 1) {
      #pragma unroll
      for (int hh = 0; hh < 2; hh++) {
        *(floatx4*)(&sK[nxt][hh][wOff])     = kp[hh][0];
        *(floatx4*)(&sK[nxt][hh][wOff + 8]) = kp[hh][1];
        *(floatx4*)(&sV[nxt][hh][wOff])     = vp[hh][0];
        *(floatx4*)(&sV[nxt][hh][wOff + 8]) = vp[hh][1];
      }
    }
    {
      int k2 = ((it + 2) & (NT - 1)) * 64;
      #pragma unroll
      for (int hh = 0; hh < 2; hh++) {
        kp[hh][0] = *(const floatx4*)(gK[hh] + (size_t)(k2) * RS);
        kp[hh][1] = *(const floatx4*)(gK[hh] + (size_t)(k2) * RS + 8);
        vp[hh][0] = *(const floatx4*)(gV[hh] + k2);
        vp[hh][1] = *(const floatx4*)(gV[hh] + k2 + 8);
      }
    }

    // bias tile loaded ONCE, used by both heads
    floatx4 bl[8];
    #pragma unroll
    for (int cc = 0; cc < 2; cc++)
      #pragma unroll
      for (int rg = 0; rg < 4; rg++)
        bl[cc * 4 + rg] = *(const floatx4*)(bp + kt + cc * 32 + 8 * rg);

    #pragma unroll
    for (int hh = 0; hh < 2; hh++) {
      // S^T: D[m=k][n=q]
      floatx16 st[2];
      #pragma unroll
      for (int cc = 0; cc < 2; cc++) {
        floatx16 s;
        #pragma unroll
        for (int r = 0; r < 16; r++) s[r] = 0.f;
        #pragma unroll
        for (int ks = 0; ks < 4; ks++) {
          short8 kf = *(const short8*)(&sK[cur][hh][(cc * 32 + l32) * 72 + 16 * ks + 8 * hl]);
          s = __builtin_amdgcn_mfma_f32_32x32x16_bf16(kf, qf[hh][ks], s, 0, 0, 0);
        }
        st[cc] = s;
      }

      // p = exp2(s); l += p; pack p*bias into 32x32x8 A-frags
      short4v pf[2][4];
      #pragma unroll
      for (int cc = 0; cc < 2; cc++)
        #pragma unroll
        for (int rg = 0; rg < 4; rg++) {
          float p0 = __builtin_amdgcn_exp2f(st[cc][rg * 4 + 0]);
          float p1 = __builtin_amdgcn_exp2f(st[cc][rg * 4 + 1]);
          float p2 = __builtin_amdgcn_exp2f(st[cc][rg * 4 + 2]);
          float p3 = __builtin_amdgcn_exp2f(st[cc][rg * 4 + 3]);
          l_run[hh] += (p0 + p1) + (p2 + p3);
          floatx4 bv = bl[cc * 4 + rg];
          unsigned int lo = pkbf(p0 * bv[0], p1 * bv[1]);
          unsigned int hi = pkbf(p2 * bv[2], p3 * bv[3]);
          union { unsigned int u[2]; short4v s4; } u;
          u.u[0] = lo; u.u[1] = hi;
          pf[cc][rg] = u.s4;
        }

      // O += P @ V : 32x32x8, A=pf (regs), B=V[k][d] from sV[d][k]
      #pragma unroll
      for (int cc = 0; cc < 2; cc++)
        #pragma unroll
        for (int g2 = 0; g2 < 4; g2++) {
          int kcol = cc * 32 + 8 * g2 + 4 * hl;
          short4v vf0 = *(const short4v*)(&sV[cur][hh][(l32)      * 72 + kcol]);
          short4v vf1 = *(const short4v*)(&sV[cur][hh][(32 + l32) * 72 + kcol]);
          oacc[hh][0] = __builtin_amdgcn_mfma_f32_32x32x8bf16_1k(pf[cc][g2], vf0, oacc[hh][0], 0, 0, 0);
          oacc[hh][1] = __builtin_amdgcn_mfma_f32_32x32x8bf16_1k(pf[cc][g2], vf1, oacc[hh][1], 0, 0, 0);
        }
    }
  }

  // write partials per head: l per q-row (hl==0 lanes), unnormalized O fp32
  #pragma unroll
  for (int hh = 0; hh < 2; hh++) {
    int h = hp * 2 + hh;
    const size_t pidx = ((size_t)(b * NSPLIT + split) * H_ + h) * (S_ / 128) + qtile;
    float* Oslab = Opart + pidx * (128 * 64);
    float* Lslab = Lpart + pidx * 128;
    float lsum = l_run[hh] + __shfl_xor(l_run[hh], 32);
    if (hl == 0) Lslab[wave * 32 + l32] = lsum;
    #pragma unroll
    for (int r = 0; r < 16; r++) {
      int q_local = wave * 32 + (r & 3) + 8 * (r >> 2) + 4 * hl;
      Oslab[(size_t)q_local * 64 + l32]      = oacc[hh][0][r];
      Oslab[(size_t)q_local * 64 + 32 + l32] = oacc[hh][1][r];
    }
  }
}

// ---------------- combine: Ab[b,q,h,d] = (O0+O1) / (l0+l1), bf16 ----------------
// grid (S/128, H, B), 256 threads; thread t: q = t>>1, d-half = (t&1)*32
__global__ __launch_bounds__(256) void combine(
    const float* __restrict__ Opart, const float* __restrict__ Lpart,
    unsigned short* __restrict__ Ab)
{
  int qt = blockIdx.x, h = blockIdx.y, b = blockIdx.z;
  int t = threadIdx.x;
  int q = t >> 1, d0 = (t & 1) * 32;
  size_t p0 = ((size_t)(b * NSPLIT + 0) * H_ + h) * (S_ / 128) + qt;
  size_t p1 = ((size_t)(b * NSPLIT + 1) * H_ + h) * (S_ / 128) + qt;
  float linv = __builtin_amdgcn_rcpf(Lpart[p0 * 128 + q] + Lpart[p1 * 128 + q]);
  const float* O0 = Opart + p0 * (128 * 64) + (size_t)q * 64 + d0;
  const float* O1 = Opart + p1 * (128 * 64) + (size_t)q * 64 + d0;
  unsigned short* dst = Ab + ((size_t)(b * S_ + qt * 128 + q) * H_ + h) * D_ + d0;
  #pragma unroll
  for (int i = 0; i < 8; i++) {
    floatx4 a = *(const floatx4*)(O0 + 4 * i);
    floatx4 c = *(const floatx4*)(O1 + 4 * i);
    a = a + c;
    unsigned int w[2];
    w[0] = pkbf(a[0] * linv, a[1] * linv);
    w[1] = pkbf(a[2] * linv, a[3] * linv);
    *(unsigned long long*)(dst + 4 * i) = *(unsigned long long*)w;
  }
}

// ---------------- launch ----------------
extern "C" void kernel_launch(void* const* d_in, const int* in_sizes, int n_in,
                              void* d_out, int out_size, void* d_ws, size_t ws_size,
                              hipStream_t stream) {
  (void)in_sizes; (void)n_in; (void)out_size; (void)ws_size;
  const float* x    = (const float*)d_in[0];
  const float* sins = (const float*)d_in[1];
  const float* ab   = (const float*)d_in[2];
  const float* Wq   = (const float*)d_in[3];
  const float* bq   = (const float*)d_in[4];
  const float* Wk   = (const float*)d_in[5];
  const float* bk   = (const float*)d_in[6];
  const float* Wv   = (const float*)d_in[7];
  const float* bv   = (const float*)d_in[8];
  const float* Wo   = (const float*)d_in[9];
  float* out = (float*)d_out;
  char* ws = (char*)d_ws;

  unsigned short* xb  = (unsigned short*)(ws);                       // 8 MB
  unsigned short* Wqt = (unsigned short*)(ws + ((size_t) 8 << 20));  // 2 MB each
  unsigned short* Wkt = (unsigned short*)(ws + ((size_t)10 << 20));
  unsigned short* Wvt = (unsigned short*)(ws + ((size_t)12 << 20));
  unsigned short* Wot = (unsigned short*)(ws + ((size_t)14 << 20));
  unsigned short* Qb  = (unsigned short*)(ws + ((size_t)16 << 20));  // 8 MB
  unsigned short* Kb  = (unsigned short*)(ws + ((size_t)24 << 20));  // 8 MB
  unsigned short* Vtb = (unsigned short*)(ws + ((size_t)32 << 20));  // 8 MB [b][h][d][s]
  unsigned short* Ab  = (unsigned short*)(ws + ((size_t)40 << 20));  // 8 MB
  float*          Opart = (float*)(ws + ((size_t)48 << 20));         // 32 MB
  float*          Lpart = (float*)(ws + ((size_t)80 << 20));         // 512 KB

  const float c1 = 0.125f * 1.44269504088896f;  // 1/sqrt(D) * log2(e), folded into Q

  cast_bf16<<<dim3((M_ * HID_) / (256 * 4)), dim3(256), 0, stream>>>(x, xb);
  transW<<<dim3(32, 32, 4), dim3(32, 8), 0, stream>>>(Wq, Wk, Wv, Wo, Wqt, Wkt, Wvt, Wot);
  gemm_bt<0><<<dim3(8, 32, 3), dim3(256), 0, stream>>>(xb, Wqt, Wkt, Wvt, bq, bk, bv,
                                                       Qb, Kb, Vtb, sins, c1);
  attn<<<dim3((H_ / 2) * 64), dim3(256), 0, stream>>>(Qb, Kb, Vtb, ab, Opart, Lpart);
  combine<<<dim3(S_ / 128, H_, B_), dim3(256), 0, stream>>>(Opart, Lpart, Ab);
  gemm_bt<1><<<dim3(8, 32, 1), dim3(256), 0, stream>>>(Ab, Wot, Wot, Wot,
                                                       nullptr, nullptr, nullptr,
                                                       out, out, out, sins, 1.f);
}

// Round 9
// 283.657 us; speedup vs baseline: 1.0835x; 1.0835x over previous
//
#include <hip/hip_runtime.h>
#include <hip/hip_bf16.h>
#include <math.h>

#define B_   2
#define S_   2048
#define HID_ 1024
#define D_   64
#define H_   16
#define ROT_ 32
#define M_   (B_*S_)
#define NSPLIT 2
#define KSPAN (S_ / NSPLIT)      // 1024 k per split
#define NT    (KSPAN / 64)       // 16 tiles per split

typedef __attribute__((ext_vector_type(4))) short  short4v;
typedef __attribute__((ext_vector_type(8))) short  short8;
typedef __attribute__((ext_vector_type(4))) float  floatx4;
typedef __attribute__((ext_vector_type(16))) float floatx16;

__device__ __forceinline__ float bf2f(unsigned short u) {
  unsigned int x = ((unsigned int)u) << 16;
  return __builtin_bit_cast(float, x);
}
__device__ __forceinline__ unsigned short f2bf(float f) {
  unsigned int x = __builtin_bit_cast(unsigned int, f);
  x += 0x7fffu + ((x >> 16) & 1u);   // RNE; inputs finite
  return (unsigned short)(x >> 16);
}
// HW packed f32x2 -> bf16x2 (v_cvt_pk_bf16_f32 on gfx950)
__device__ __forceinline__ unsigned int pkbf(float a, float b) {
  __hip_bfloat162 h = __float22bfloat162_rn(float2{a, b});
  unsigned int u; __builtin_memcpy(&u, &h, 4); return u;
}
// async global->LDS, 16B per lane; lds dest = wave-uniform base + lane*16
__device__ __forceinline__ void gload_lds16(const unsigned short* g, unsigned short* l) {
  __builtin_amdgcn_global_load_lds(
      (const __attribute__((address_space(1))) unsigned int*)g,
      (__attribute__((address_space(3))) unsigned int*)l, 16, 0, 0);
}

// ---------------- cast x (fp32 -> bf16) ----------------
__global__ void cast_bf16(const float* __restrict__ in, unsigned short* __restrict__ out) {
  int i = (blockIdx.x * 256 + threadIdx.x) * 4;
  floatx4 v = *(const floatx4*)(in + i);
  unsigned short o[4];
  o[0] = f2bf(v[0]); o[1] = f2bf(v[1]); o[2] = f2bf(v[2]); o[3] = f2bf(v[3]);
  *(unsigned long long*)(out + i) = *(unsigned long long*)o;
}

// ------------- transpose + cast weights: T[n][k] = bf16(W[k][n]) -------------
__global__ void transW(const float* __restrict__ W0, const float* __restrict__ W1,
                       const float* __restrict__ W2, const float* __restrict__ W3,
                       unsigned short* __restrict__ T0, unsigned short* __restrict__ T1,
                       unsigned short* __restrict__ T2, unsigned short* __restrict__ T3) {
  const float* W; unsigned short* T;
  int z = blockIdx.z;
  if (z == 0)      { W = W0; T = T0; }
  else if (z == 1) { W = W1; T = T1; }
  else if (z == 2) { W = W2; T = T2; }
  else             { W = W3; T = T3; }
  __shared__ float tile[32][33];
  int bx = blockIdx.x * 32, by = blockIdx.y * 32;
  int tx = threadIdx.x, ty = threadIdx.y;
  #pragma unroll
  for (int j = 0; j < 4; j++)
    tile[ty + j*8][tx] = W[(size_t)(by + ty + j*8) * HID_ + bx + tx];
  __syncthreads();
  #pragma unroll
  for (int j = 0; j < 4; j++)
    T[(size_t)(bx + ty + j*8) * HID_ + by + tx] = f2bf(tile[tx][ty + j*8]);
}

// ------- bias pre-swizzle: fp32 [b][q][k] -> bf16 tiles in attn lane order -------
// OUT[(((b*64+qb)*32+kb)*8 + g)*256 + hl*128 + l32*4 + e] =
//   bf16(bias[b][qb*32+l32][kb*64 + (g>>2)*32 + (g&3)*8 + hl*4 + e])
// Attn then reads 8B/lane fully contiguous (512B per wave instruction).
__global__ __launch_bounds__(256) void prepB(const float* __restrict__ bias,
                                             unsigned short* __restrict__ out) {
  int qb = blockIdx.x, kb = blockIdx.y, b = blockIdx.z;
  int t = threadIdx.x;
  int l32 = t & 31, g = t >> 5;
  int cc = g >> 2, rg = g & 3;
  const float* src = bias + ((size_t)b * S_ + qb * 32 + l32) * S_ + kb * 64 + cc * 32 + rg * 8;
  unsigned short* dst = out + ((((size_t)(b * 64 + qb)) * 32 + kb) * 8 + g) * 256 + l32 * 4;
  floatx4 v0 = *(const floatx4*)(src);
  floatx4 v1 = *(const floatx4*)(src + 4);
  unsigned int w0[2], w1[2];
  w0[0] = pkbf(v0[0], v0[1]); w0[1] = pkbf(v0[2], v0[3]);
  w1[0] = pkbf(v1[0], v1[1]); w1[1] = pkbf(v1[2], v1[3]);
  *(unsigned long long*)(dst)       = *(unsigned long long*)w0;   // hl=0
  *(unsigned long long*)(dst + 128) = *(unsigned long long*)w1;   // hl=1
}

// ---------------- GEMM: C[M,N] = A[M,K] @ Bt[N,K]^T (+bias) ----------------
// MODE 0: QKV producer. z=0: Q head-major [b][h][s][d], rope + scale c1.
//         z=1: K head-major [b][h][s][d], rope.
//         z=2: V as contiguous 8KB (head,kblock) tiles [b][h][kb][d][64].
// MODE 1: fp32 row-major out (final projection).
template <int MODE>
__global__ __launch_bounds__(256) void gemm_bt(
    const unsigned short* __restrict__ A,
    const unsigned short* __restrict__ Bt0, const unsigned short* __restrict__ Bt1,
    const unsigned short* __restrict__ Bt2,
    const float* __restrict__ bias0, const float* __restrict__ bias1,
    const float* __restrict__ bias2,
    void* __restrict__ out0, void* __restrict__ out1, void* __restrict__ out2,
    const float* __restrict__ sins, float sc0)
{
  const unsigned short* Bt; const float* bias; void* Out; float sc;
  if (blockIdx.z == 0)      { Bt = Bt0; bias = bias0; Out = out0; sc = sc0; }
  else if (blockIdx.z == 1) { Bt = Bt1; bias = bias1; Out = out1; sc = 1.f; }
  else                      { Bt = Bt2; bias = bias2; Out = out2; sc = 1.f; }
  const int K = HID_, N = HID_;
  int m0 = blockIdx.y * 128, n0 = blockIdx.x * 128;
  __shared__ alignas(16) unsigned short sA[128 * 32];
  __shared__ alignas(16) unsigned short sB[128 * 32];
  int t = threadIdx.x;
  int lane = t & 63, wave = t >> 6;
  int quad = lane >> 4, l16 = lane & 15;
  int wr = wave >> 1, wc = wave & 1;

  int srow = (lane >> 2), scol = (lane & 3) * 8;
  const unsigned short* gA0 = A  + (size_t)(m0 + wave*32 +  0 + srow) * K + scol;
  const unsigned short* gA1 = A  + (size_t)(m0 + wave*32 + 16 + srow) * K + scol;
  const unsigned short* gB0 = Bt + (size_t)(n0 + wave*32 +  0 + srow) * K + scol;
  const unsigned short* gB1 = Bt + (size_t)(n0 + wave*32 + 16 + srow) * K + scol;
  unsigned short* lA0 = sA + (wave*32 +  0) * 32;
  unsigned short* lA1 = sA + (wave*32 + 16) * 32;
  unsigned short* lB0 = sB + (wave*32 +  0) * 32;
  unsigned short* lB1 = sB + (wave*32 + 16) * 32;

  floatx4 acc[4][4];
  #pragma unroll
  for (int i = 0; i < 4; i++)
    #pragma unroll
    for (int j = 0; j < 4; j++)
      acc[i][j] = (floatx4){0.f, 0.f, 0.f, 0.f};

  for (int k0 = 0; k0 < K; k0 += 32) {
    gload_lds16(gA0 + k0, lA0);
    gload_lds16(gA1 + k0, lA1);
    gload_lds16(gB0 + k0, lB0);
    gload_lds16(gB1 + k0, lB1);
    __syncthreads();
    short8 af[4], bf[4];
    #pragma unroll
    for (int i = 0; i < 4; i++) {
      af[i] = *(const short8*)(sA + (wr * 64 + i * 16 + l16) * 32 + quad * 8);
      bf[i] = *(const short8*)(sB + (wc * 64 + i * 16 + l16) * 32 + quad * 8);
    }
    #pragma unroll
    for (int i = 0; i < 4; i++)
      #pragma unroll
      for (int j = 0; j < 4; j++)
        acc[i][j] = __builtin_amdgcn_mfma_f32_16x16x32_bf16(af[i], bf[j], acc[i][j], 0, 0, 0);
    __syncthreads();
  }

  // Epilogue. C/D layout: col = lane&15, row = quad*4 + reg.
  #pragma unroll
  for (int i = 0; i < 4; i++) {
    int mbase = m0 + wr * 64 + i * 16 + quad * 4;
    #pragma unroll
    for (int j = 0; j < 4; j++) {
      int n = n0 + wc * 64 + j * 16 + l16;
      float bv = bias ? bias[n] : 0.f;
      if (MODE == 1) {
        #pragma unroll
        for (int r = 0; r < 4; r++)
          ((float*)Out)[(size_t)(mbase + r) * N + n] = acc[i][j][r] + bv;
      } else if (blockIdx.z == 2) {
        // V tiles: idx = (((b*H+h)*(S/64) + s/64)*D + d)*64 + s%64, 4 s packed
        int bb = mbase >> 11, ss = mbase & 2047;
        int hh = n >> 6, dd = n & 63;
        unsigned short pk[4];
        #pragma unroll
        for (int r = 0; r < 4; r++) pk[r] = f2bf(acc[i][j][r] + bv);
        size_t idx = ((((size_t)(bb * H_ + hh) * (S_ / 64) + (ss >> 6)) * D_ + dd) * 64) + (ss & 63);
        *(unsigned long long*)((unsigned short*)Out + idx) = *(unsigned long long*)pk;
      } else if (j < 2) {
        // rope columns (d = j*16+l16 < 32), head-major [b][h][s][d]
        int jh = j * 16 + l16;
        int hh = n >> 6, dd = n & 63;
        #pragma unroll
        for (int r = 0; r < 4; r++) {
          int row = mbase + r, bb = row >> 11, ss = row & 2047;
          float sn = sins[((size_t)(bb * 2 + 0) * S_ + ss) * ROT_ + jh];
          float cs = sins[((size_t)(bb * 2 + 1) * S_ + ss) * ROT_ + jh];
          float f = (jh & 1) ? (cs + sn) : (cs - sn);
          ((unsigned short*)Out)[((size_t)(bb * H_ + hh) * S_ + ss) * D_ + dd] =
              f2bf((acc[i][j][r] + bv) * f * sc);
        }
      } else {
        int hh = n >> 6, dd = n & 63;
        #pragma unroll
        for (int r = 0; r < 4; r++) {
          int row = mbase + r, bb = row >> 11, ss = row & 2047;
          ((unsigned short*)Out)[((size_t)(bb * H_ + hh) * S_ + ss) * D_ + dd] =
              f2bf((acc[i][j][r] + bv) * sc);
        }
      }
    }
  }
}

// ------ flash attention v6: S^T trick + split-K + fully-coalesced global loads ------
// Q/K head-major, V in 8KB tiles, bias pre-swizzled bf16: every hot global load is
// lane-contiguous. XCD-swizzled 1D grid (1024 blocks).
__global__ __launch_bounds__(256) void attn(
    const unsigned short* __restrict__ Q, const unsigned short* __restrict__ Kh,
    const unsigned short* __restrict__ Vt, const unsigned short* __restrict__ Bsw,
    float* __restrict__ Opart, float* __restrict__ Lpart)
{
  int gid = blockIdx.x;
  int c = gid & 7, h = (gid >> 3) & 15, g = gid >> 7;
  int combo = g * 8 + c;            // [0,64)
  int qtile = combo & 15;
  int rest  = combo >> 4;
  int b = rest & 1, split = rest >> 1;

  int t = threadIdx.x;
  int lane = t & 63, wave = t >> 6;
  int l32 = lane & 31, hl = lane >> 5;
  int q0 = qtile * 128 + wave * 32;
  int kbase = split * KSPAN;
  const size_t pidx = ((size_t)(b * NSPLIT + split) * H_ + h) * (S_ / 128) + qtile;
  float* Oslab = Opart + pidx * (128 * 64);
  float* Lslab = Lpart + pidx * 128;

  __shared__ alignas(16) unsigned short sK[2][64 * 72];  // [k][d] pad 72
  __shared__ alignas(16) unsigned short sV[2][64 * 72];  // [d][k] pad 72

  // head-major bases; K tile (64x64) is 8KB contiguous, V tile likewise
  const unsigned short* Qbase = Q + ((size_t)(b * H_ + h) * S_) * D_;
  const unsigned short* gK0 = Kh + ((size_t)(b * H_ + h) * S_ + kbase) * D_ + t * 16;
  const unsigned short* gV0 = Vt + (((size_t)(b * H_ + h) * (S_ / 64) + split * NT) * D_) * 64 + t * 16;
  // swizzled bias: per lane 8B contiguous per group
  const unsigned short* bt0 = Bsw +
      (((size_t)(b * 64 + (q0 >> 5)) * 32 + split * NT) * 8) * 256 + hl * 128 + l32 * 4;

  // Q B-frags (n=q=lane&31, k=d=16s+8hl+j)
  short8 qf[4];
  {
    const unsigned short* qp = Qbase + (size_t)(q0 + l32) * D_ + 8 * hl;
    qf[0] = *(const short8*)(qp);
    qf[1] = *(const short8*)(qp + 16);
    qf[2] = *(const short8*)(qp + 32);
    qf[3] = *(const short8*)(qp + 48);
  }

  // LDS staging slot for this thread (matches the t*16-element contiguous load)
  int srow = t >> 2, sq = t & 3;
  const int wOff = srow * 72 + sq * 16;

  float l_run = 0.f;
  floatx16 o0, o1;
  #pragma unroll
  for (int r = 0; r < 16; r++) { o0[r] = 0.f; o1[r] = 0.f; }

  // tile 0 -> LDS buf 0
  floatx4 kp[2], vp[2];
  kp[0] = *(const floatx4*)(gK0);     kp[1] = *(const floatx4*)(gK0 + 8);
  vp[0] = *(const floatx4*)(gV0);     vp[1] = *(const floatx4*)(gV0 + 8);
  *(floatx4*)(&sK[0][wOff])     = kp[0];
  *(floatx4*)(&sK[0][wOff + 8]) = kp[1];
  *(floatx4*)(&sV[0][wOff])     = vp[0];
  *(floatx4*)(&sV[0][wOff + 8]) = vp[1];
  // prefetch tile 1 (tiles are 4096 elements apart)
  kp[0] = *(const floatx4*)(gK0 + 4096);
  kp[1] = *(const floatx4*)(gK0 + 4096 + 8);
  vp[0] = *(const floatx4*)(gV0 + 4096);
  vp[1] = *(const floatx4*)(gV0 + 4096 + 8);

  for (int it = 0; it < NT; ++it) {
    int cur = it & 1, nxt = cur ^ 1;
    __syncthreads();

    if (it < NT - 1) {
      *(floatx4*)(&sK[nxt][wOff])     = kp[0];
      *(floatx4*)(&sK[nxt][wOff + 8]) = kp[1];
      *(floatx4*)(&sV[nxt][wOff])     = vp[0];
      *(floatx4*)(&sV[nxt][wOff + 8]) = vp[1];
    }
    {
      size_t o = (size_t)(((it + 2) & (NT - 1))) * 4096;
      kp[0] = *(const floatx4*)(gK0 + o);
      kp[1] = *(const floatx4*)(gK0 + o + 8);
      vp[0] = *(const floatx4*)(gV0 + o);
      vp[1] = *(const floatx4*)(gV0 + o + 8);
    }

    // bias tile: 8 coalesced 8B loads (bf16x4 per lane)
    unsigned long long braw[8];
    {
      const unsigned short* bt = bt0 + (size_t)it * 2048;
      #pragma unroll
      for (int gg = 0; gg < 8; gg++)
        braw[gg] = *(const unsigned long long*)(bt + gg * 256);
    }

    // S^T: D[m=k][n=q]
    floatx16 st[2];
    #pragma unroll
    for (int cc = 0; cc < 2; cc++) {
      floatx16 s;
      #pragma unroll
      for (int r = 0; r < 16; r++) s[r] = 0.f;
      #pragma unroll
      for (int ks = 0; ks < 4; ks++) {
        short8 kf = *(const short8*)(&sK[cur][(cc * 32 + l32) * 72 + 16 * ks + 8 * hl]);
        s = __builtin_amdgcn_mfma_f32_32x32x16_bf16(kf, qf[ks], s, 0, 0, 0);
      }
      st[cc] = s;
    }

    // p = exp2(s); l += p; pack p*bias into 32x32x8 A-frags
    short4v pf[2][4];
    #pragma unroll
    for (int cc = 0; cc < 2; cc++)
      #pragma unroll
      for (int rg = 0; rg < 4; rg++) {
        float p0 = __builtin_amdgcn_exp2f(st[cc][rg * 4 + 0]);
        float p1 = __builtin_amdgcn_exp2f(st[cc][rg * 4 + 1]);
        float p2 = __builtin_amdgcn_exp2f(st[cc][rg * 4 + 2]);
        float p3 = __builtin_amdgcn_exp2f(st[cc][rg * 4 + 3]);
        l_run += (p0 + p1) + (p2 + p3);
        unsigned long long u = braw[cc * 4 + rg];
        float b0 = bf2f((unsigned short)(u));
        float b1 = bf2f((unsigned short)(u >> 16));
        float b2 = bf2f((unsigned short)(u >> 32));
        float b3 = bf2f((unsigned short)(u >> 48));
        unsigned int lo = pkbf(p0 * b0, p1 * b1);
        unsigned int hi = pkbf(p2 * b2, p3 * b3);
        union { unsigned int w[2]; short4v s4; } uu;
        uu.w[0] = lo; uu.w[1] = hi;
        pf[cc][rg] = uu.s4;
      }

    // O += P @ V : 32x32x8, A=pf (regs), B=V[k][d] from sV[d][k]
    #pragma unroll
    for (int cc = 0; cc < 2; cc++)
      #pragma unroll
      for (int g2 = 0; g2 < 4; g2++) {
        int kcol = cc * 32 + 8 * g2 + 4 * hl;
        short4v vf0 = *(const short4v*)(&sV[cur][(l32)      * 72 + kcol]);
        short4v vf1 = *(const short4v*)(&sV[cur][(32 + l32) * 72 + kcol]);
        o0 = __builtin_amdgcn_mfma_f32_32x32x8bf16_1k(pf[cc][g2], vf0, o0, 0, 0, 0);
        o1 = __builtin_amdgcn_mfma_f32_32x32x8bf16_1k(pf[cc][g2], vf1, o1, 0, 0, 0);
      }
  }

  // write partials: l per q-row (hl==0 lanes), unnormalized O fp32
  float lsum = l_run + __shfl_xor(l_run, 32);
  if (hl == 0) Lslab[wave * 32 + l32] = lsum;
  #pragma unroll
  for (int r = 0; r < 16; r++) {
    int q_local = wave * 32 + (r & 3) + 8 * (r >> 2) + 4 * hl;
    Oslab[(size_t)q_local * 64 + l32]      = o0[r];
    Oslab[(size_t)q_local * 64 + 32 + l32] = o1[r];
  }
}

// ---------------- combine: Ab[b,q,h,d] = (O0+O1) / (l0+l1), bf16 ----------------
__global__ __launch_bounds__(256) void combine(
    const float* __restrict__ Opart, const float* __restrict__ Lpart,
    unsigned short* __restrict__ Ab)
{
  int qt = blockIdx.x, h = blockIdx.y, b = blockIdx.z;
  int t = threadIdx.x;
  int q = t >> 1, d0 = (t & 1) * 32;
  size_t p0 = ((size_t)(b * NSPLIT + 0) * H_ + h) * (S_ / 128) + qt;
  size_t p1 = ((size_t)(b * NSPLIT + 1) * H_ + h) * (S_ / 128) + qt;
  float linv = __builtin_amdgcn_rcpf(Lpart[p0 * 128 + q] + Lpart[p1 * 128 + q]);
  const float* O0 = Opart + p0 * (128 * 64) + (size_t)q * 64 + d0;
  const float* O1 = Opart + p1 * (128 * 64) + (size_t)q * 64 + d0;
  unsigned short* dst = Ab + ((size_t)(b * S_ + qt * 128 + q) * H_ + h) * D_ + d0;
  #pragma unroll
  for (int i = 0; i < 8; i++) {
    floatx4 a = *(const floatx4*)(O0 + 4 * i);
    floatx4 c = *(const floatx4*)(O1 + 4 * i);
    a = a + c;
    unsigned int w[2];
    w[0] = pkbf(a[0] * linv, a[1] * linv);
    w[1] = pkbf(a[2] * linv, a[3] * linv);
    *(unsigned long long*)(dst + 4 * i) = *(unsigned long long*)w;
  }
}

// ---------------- launch ----------------
extern "C" void kernel_launch(void* const* d_in, const int* in_sizes, int n_in,
                              void* d_out, int out_size, void* d_ws, size_t ws_size,
                              hipStream_t stream) {
  (void)in_sizes; (void)n_in; (void)out_size; (void)ws_size;
  const float* x    = (const float*)d_in[0];
  const float* sins = (const float*)d_in[1];
  const float* ab   = (const float*)d_in[2];
  const float* Wq   = (const float*)d_in[3];
  const float* bq   = (const float*)d_in[4];
  const float* Wk   = (const float*)d_in[5];
  const float* bk   = (const float*)d_in[6];
  const float* Wv   = (const float*)d_in[7];
  const float* bv   = (const float*)d_in[8];
  const float* Wo   = (const float*)d_in[9];
  float* out = (float*)d_out;
  char* ws = (char*)d_ws;

  unsigned short* xb  = (unsigned short*)(ws);                       // 8 MB
  unsigned short* Wqt = (unsigned short*)(ws + ((size_t) 8 << 20));  // 2 MB each
  unsigned short* Wkt = (unsigned short*)(ws + ((size_t)10 << 20));
  unsigned short* Wvt = (unsigned short*)(ws + ((size_t)12 << 20));
  unsigned short* Wot = (unsigned short*)(ws + ((size_t)14 << 20));
  unsigned short* Qb  = (unsigned short*)(ws + ((size_t)16 << 20));  // 8 MB [b][h][s][d]
  unsigned short* Kb  = (unsigned short*)(ws + ((size_t)24 << 20));  // 8 MB [b][h][s][d]
  unsigned short* Vtb = (unsigned short*)(ws + ((size_t)32 << 20));  // 8 MB V tiles
  unsigned short* Ab  = (unsigned short*)(ws + ((size_t)40 << 20));  // 8 MB
  unsigned short* Bsw = (unsigned short*)(ws + ((size_t)48 << 20));  // 16.8 MB bias bf16 swz
  float*          Opart = (float*)(ws + ((size_t)65 << 20));         // 32 MB
  float*          Lpart = (float*)(ws + ((size_t)97 << 20));         // 512 KB

  const float c1 = 0.125f * 1.44269504088896f;  // 1/sqrt(D) * log2(e), folded into Q

  prepB<<<dim3(64, 32, 2), dim3(256), 0, stream>>>(ab, Bsw);
  cast_bf16<<<dim3((M_ * HID_) / (256 * 4)), dim3(256), 0, stream>>>(x, xb);
  transW<<<dim3(32, 32, 4), dim3(32, 8), 0, stream>>>(Wq, Wk, Wv, Wo, Wqt, Wkt, Wvt, Wot);
  gemm_bt<0><<<dim3(8, 32, 3), dim3(256), 0, stream>>>(xb, Wqt, Wkt, Wvt, bq, bk, bv,
                                                       Qb, Kb, Vtb, sins, c1);
  attn<<<dim3((S_ / 128) * H_ * B_ * NSPLIT), dim3(256), 0, stream>>>(Qb, Kb, Vtb, Bsw,
                                                                      Opart, Lpart);
  combine<<<dim3(S_ / 128, H_, B_), dim3(256), 0, stream>>>(Opart, Lpart, Ab);
  gemm_bt<1><<<dim3(8, 32, 1), dim3(256), 0, stream>>>(Ab, Wot, Wot, Wot,
                                                       nullptr, nullptr, nullptr,
                                                       out, out, out, sins, 1.f);
}